// Round 4
// baseline (242.215 us; speedup 1.0000x reference)
//
#include <hip/hip_runtime.h>
#include <hip/hip_bf16.h>

#define STATE 16
#define DNA_C 4
#define HID   128
#define FAN1  52
#define HH    256
#define WW    256
#define HW    (HH * WW)

typedef unsigned short u16;
typedef unsigned int   u32;
typedef short bf8 __attribute__((ext_vector_type(8)));
typedef float f32x4 __attribute__((ext_vector_type(4)));

__device__ __forceinline__ u32 pk(float a, float b) {
    __hip_bfloat162 t = __float22bfloat162_rn(make_float2(a, b));  // v_cvt_pk_bf16_f32
    union { __hip_bfloat162 h; u32 u; } c; c.h = t; return c.u;
}
__device__ __forceinline__ u16 f2bf(float f) {
    union { __hip_bfloat16 h; u16 u; } c; c.h = __float2bfloat16(f); return c.u;
}

// w1 [128][52] f32 -> w1b [128][64] bf16 with the k-permutation baked in
// (new k = 16w + t : t0-3 = x ch 4w..4w+3, t4-7 = gx, t8-11 = gy, t12-15 = dna(w==0)/pad)
// w2 [16][128] -> bf16 unpermuted.
__global__ void prep_weights(const float* __restrict__ w1, const float* __restrict__ w2,
                             u16* __restrict__ wb) {
    int i = blockIdx.x * 256 + threadIdx.x;
    if (i < 128 * 64) {
        int r = i >> 6, knew = i & 63;
        int w = knew >> 4, t = knew & 15;
        float v = 0.f;
        if (t < 4)        v = w1[r * FAN1 + 4 * w + t];
        else if (t < 8)   v = w1[r * FAN1 + 16 + 4 * w + (t - 4)];
        else if (t < 12)  v = w1[r * FAN1 + 32 + 4 * w + (t - 8)];
        else if (w == 0)  v = w1[r * FAN1 + 48 + (t - 12)];
        wb[i] = f2bf(v);
    } else if (i < 128 * 64 + 16 * 128) {
        wb[i] = f2bf(w2[i - 128 * 64]);
    }
}

__global__ __launch_bounds__(256, 5) void update_net3(
    const float* __restrict__ x,    // [B,16,256,256]
    const float* __restrict__ dna,  // [B,4,256,256]
    const u16*   __restrict__ wb,   // permuted bf16 w1 [128][64], w2 [16][128]
    float* __restrict__ out)        // [B,16,256,256]
{
    // feat: [256 px][8 kchunks of 16B], chunk swizzle: c ^= (px>>2)&7.  32 KB -> 5 blocks/CU.
    // Wave w's region (rows [64w,64w+64)) is wave-private after the barrier; h overlays it.
    __shared__ __align__(16) u16 feat_lds[256 * 64];

    const int tid  = threadIdx.x;
    const int lane = tid & 63;
    const int w    = tid >> 6;
    const int row  = blockIdx.x;
    const int b    = row >> 8;
    const int y    = row & 255;
    const bool ht  = (y > 0), hb = (y < HH - 1);   // block-uniform

    // ---------- feature phase: wave w -> channels 4w..4w+3, full 256-px row, 4 px/lane ----------
    {
        const int px0 = lane * 4;
        const float* base = x + (((size_t)(b * STATE + 4 * w)) * HH + y) * WW + px0;

        f32x4 xm[4], gx[4], gy[4];
        #pragma unroll
        for (int c = 0; c < 4; ++c) {
            const float* p = base + (size_t)c * HW;
            f32x4 m4 = *(const f32x4*)p;
            f32x4 t4 = {0.f,0.f,0.f,0.f}, b4 = {0.f,0.f,0.f,0.f};
            if (ht) t4 = *(const f32x4*)(p - WW);
            if (hb) b4 = *(const f32x4*)(p + WW);
            f32x4 cs, d;
            #pragma unroll
            for (int i = 0; i < 4; ++i) {
                cs[i] = fmaf(2.f, m4[i], t4[i] + b4[i]);   // colsum t+2m+b
                d[i]  = b4[i] - t4[i];
            }
            float csL = __shfl_up(cs[3], 1);
            float csR = __shfl_down(cs[0], 1);
            float dL  = __shfl_up(d[3], 1);
            float dR  = __shfl_down(d[0], 1);
            if (lane == 0)  { csL = 0.f; dL = 0.f; }       // image left border (zero pad)
            if (lane == 63) { csR = 0.f; dR = 0.f; }       // image right border
            xm[c] = m4;
            gx[c][0] = cs[1] - csL;   gx[c][1] = cs[2] - cs[0];
            gx[c][2] = cs[3] - cs[1]; gx[c][3] = csR - cs[2];
            gy[c][0] = fmaf(2.f, d[0], dL + d[1]);
            gy[c][1] = fmaf(2.f, d[1], d[0] + d[2]);
            gy[c][2] = fmaf(2.f, d[2], d[1] + d[3]);
            gy[c][3] = fmaf(2.f, d[3], d[2] + dR);
        }
        f32x4 dn[4] = {{0,0,0,0},{0,0,0,0},{0,0,0,0},{0,0,0,0}};
        if (w == 0) {
            #pragma unroll
            for (int dc = 0; dc < 4; ++dc)
                dn[dc] = *(const f32x4*)(dna + (((size_t)(b * DNA_C + dc)) * HH + y) * WW + px0);
        }
        const int s = lane & 7;   // (px>>2)&7 == lane&7 for all 4 px of this lane
        #pragma unroll
        for (int i = 0; i < 4; ++i) {
            u16* rowp = &feat_lds[(px0 + i) * 64];
            uint4 c0 = make_uint4(pk(xm[0][i], xm[1][i]), pk(xm[2][i], xm[3][i]),
                                  pk(gx[0][i], gx[1][i]), pk(gx[2][i], gx[3][i]));
            uint4 c1 = make_uint4(pk(gy[0][i], gy[1][i]), pk(gy[2][i], gy[3][i]),
                                  pk(dn[0][i], dn[1][i]), pk(dn[2][i], dn[3][i]));
            *(uint4*)&rowp[8 * ((2 * w)     ^ s)] = c0;   // kchunk 2w   : x | gx
            *(uint4*)&rowp[8 * ((2 * w + 1) ^ s)] = c1;   // kchunk 2w+1 : gy | dna/pad
        }
    }

    // ---------- A fragments from global (L1-hot, shared across all blocks) ----------
    const int fj = lane & 15, fg = lane >> 4, sfj = fj & 7;
    const u16* w1b = wb;
    const u16* w2b = wb + 128 * 64;
    bf8 a1[8][2];
    #pragma unroll
    for (int m = 0; m < 8; ++m) {
        #pragma unroll
        for (int kt = 0; kt < 2; ++kt)
            a1[m][kt] = *(const bf8*)&w1b[(16 * m + fj) * 64 + 32 * kt + 8 * fg];
    }
    bf8 a2[4];
    #pragma unroll
    for (int kt = 0; kt < 4; ++kt)
        a2[kt] = *(const bf8*)&w2b[fj * 128 + 32 * kt + 8 * fg];

    __syncthreads();

    // ---------- pre-read ALL B fragments for this wave's 64 px (frees feat region for h) ----------
    bf8 bf0[4], bf1[4];
    #pragma unroll
    for (int g4 = 0; g4 < 4; ++g4) {
        const int px = w * 64 + g4 * 16 + fj;
        const int ss = (px >> 2) & 7;
        bf0[g4] = *(const bf8*)&feat_lds[px * 64 + 8 * (fg ^ ss)];        // k 0-31
        bf1[g4] = *(const bf8*)&feat_lds[px * 64 + 8 * ((4 + fg) ^ ss)];  // k 32-63
    }

    u16* hwv = &feat_lds[w * 4096];   // wave-private h [16 px][128 k] overlaying own feat rows

    #pragma unroll
    for (int g4 = 0; g4 < 4; ++g4) {
        f32x4 hacc[8];
        #pragma unroll
        for (int m = 0; m < 8; ++m) {
            f32x4 z = {0.f, 0.f, 0.f, 0.f};
            z = __builtin_amdgcn_mfma_f32_16x16x32_bf16(a1[m][0], bf0[g4], z, 0, 0, 0);
            hacc[m] = __builtin_amdgcn_mfma_f32_16x16x32_bf16(a1[m][1], bf1[g4], z, 0, 0, 0);
        }

        // relu + pack; lane holds h[k=16m+4fg+r][px=fj]
        #pragma unroll
        for (int m = 0; m < 8; ++m) {
            float h0 = fmaxf(hacc[m][0], 0.f), h1 = fmaxf(hacc[m][1], 0.f);
            float h2 = fmaxf(hacc[m][2], 0.f), h3 = fmaxf(hacc[m][3], 0.f);
            *(uint2*)&hwv[fj * 128 + 8 * ((2 * m + (fg >> 1)) ^ sfj) + 4 * (fg & 1)] =
                make_uint2(pk(h0, h1), pk(h2, h3));
        }
        asm volatile("s_waitcnt lgkmcnt(0)" ::: "memory");  // wave-local h exchange

        f32x4 uacc = {0.f, 0.f, 0.f, 0.f};
        #pragma unroll
        for (int kt = 0; kt < 4; ++kt) {
            bf8 b2 = *(const bf8*)&hwv[fj * 128 + 8 * ((4 * kt + fg) ^ sfj)];
            uacc = __builtin_amdgcn_mfma_f32_16x16x32_bf16(a2[kt], b2, uacc, 0, 0, 0);
        }

        const int xo = w * 64 + g4 * 16 + fj;
        float* po = out + (((size_t)(b * STATE + 4 * fg)) * HH + y) * WW + xo;
        #pragma unroll
        for (int rr = 0; rr < 4; ++rr)
            po[(size_t)rr * HW] = uacc[rr];
    }
}

extern "C" void kernel_launch(void* const* d_in, const int* in_sizes, int n_in,
                              void* d_out, int out_size, void* d_ws, size_t ws_size,
                              hipStream_t stream) {
    const float* x   = (const float*)d_in[0];
    const float* dna = (const float*)d_in[1];
    const float* w1  = (const float*)d_in[2];
    const float* w2  = (const float*)d_in[3];
    float* out = (float*)d_out;
    u16* wb = (u16*)d_ws;   // 10240 u16 = 20 KB

    prep_weights<<<dim3(40), dim3(256), 0, stream>>>(w1, w2, wb);

    const int B = in_sizes[0] / (STATE * HH * WW);   // 16
    update_net3<<<dim3(B * HH), dim3(256), 0, stream>>>(x, dna, wb, out);
}

// Round 5
// 235.961 us; speedup vs baseline: 1.0265x; 1.0265x over previous
//
#include <hip/hip_runtime.h>
#include <hip/hip_bf16.h>

#define STATE 16
#define DNA_C 4
#define HID   128
#define FAN1  52
#define HH    256
#define WW    256
#define HW    (HH * WW)

typedef unsigned short u16;
typedef unsigned int   u32;
typedef short bf8 __attribute__((ext_vector_type(8)));
typedef float f32x4 __attribute__((ext_vector_type(4)));

__device__ __forceinline__ u32 pk(float a, float b) {
    __hip_bfloat162 t = __float22bfloat162_rn(make_float2(a, b));  // v_cvt_pk_bf16_f32
    union { __hip_bfloat162 h; u32 u; } c; c.h = t; return c.u;
}
__device__ __forceinline__ u16 f2bf(float f) {
    union { __hip_bfloat16 h; u16 u; } c; c.h = __float2bfloat16(f); return c.u;
}

__device__ __forceinline__ void sobel1(const float* __restrict__ p,
                                       bool hl, bool hr, bool ht, bool hb,
                                       float& mc, float& gx, float& gy) {
    float tl = 0.f, tc = 0.f, tr = 0.f;
    float ml = 0.f,           mr = 0.f;
    float bl = 0.f, bc = 0.f, br = 0.f;
    mc = p[0];
    if (hl) ml = p[-1];
    if (hr) mr = p[1];
    if (ht) {
        tc = p[-WW];
        if (hl) tl = p[-WW - 1];
        if (hr) tr = p[-WW + 1];
    }
    if (hb) {
        bc = p[WW];
        if (hl) bl = p[WW - 1];
        if (hr) br = p[WW + 1];
    }
    gx = (tr - tl) + 2.f * (mr - ml) + (br - bl);
    gy = (bl + 2.f * bc + br) - (tl + 2.f * tc + tr);
}

// w1 [128][52] f32 -> bf16 [128][64] zero-padded; w2 [16][128] -> bf16 (plain k order)
__global__ void prep_weights(const float* __restrict__ w1, const float* __restrict__ w2,
                             u16* __restrict__ wb) {
    int i = blockIdx.x * 256 + threadIdx.x;   // 0..10239
    if (i < 128 * 64) {
        int r = i >> 6, k = i & 63;
        wb[i] = (k < FAN1) ? f2bf(w1[r * FAN1 + k]) : (u16)0;
    } else if (i < 128 * 64 + 16 * 128) {
        wb[i] = f2bf(w2[i - 128 * 64]);
    }
}

__global__ __launch_bounds__(256, 5) void update_net5(
    const float* __restrict__ x,    // [B,16,256,256]
    const float* __restrict__ dna,  // [B,4,256,256]
    const u16*   __restrict__ wb,   // bf16 w1 [128][64], w2 [16][128]
    float* __restrict__ out)        // [B,16,256,256]
{
    // feat: [256 px][64 k] bf16, 128B rows, 16B chunks swizzled chunk ^= px&7. 32 KB.
    // Wave wv's rows [wv*64, wv*64+64) are written and read only by wave wv.
    // h [16 px][128 k] overlays the UPPER half (rows wv*64+32..63) of the wave's region;
    // g4=2,3 B-fragments (those rows) are pre-read into registers before the first h write.
    __shared__ __align__(16) u16 feat_lds[256 * 64];

    const int tid = threadIdx.x;
    const int row = blockIdx.x;
    const int b = row >> 8;
    const int y = row & 255;

    // ---- per-thread features -> bf16 -> swizzled feat_lds[tid][*] (round-3 verbatim) ----
    {
        const int xw = tid;
        const bool hl = (xw > 0), hr = (xw < WW - 1);
        const bool ht = (y > 0),  hb = (y < HH - 1);
        const float* pb = x + (((size_t)b * STATE) * HH + y) * WW + xw;
        const int sw = tid & 7;
        u16* frow = &feat_lds[tid * 64];

        #pragma unroll
        for (int half = 0; half < 2; ++half) {
            float fm[8], fgx[8], fgy[8];
            #pragma unroll
            for (int c = 0; c < 8; ++c)
                sobel1(pb + (size_t)(8 * half + c) * HW, hl, hr, ht, hb,
                       fm[c], fgx[c], fgy[c]);
            uint4 vm  = make_uint4(pk(fm[0], fm[1]),  pk(fm[2], fm[3]),
                                   pk(fm[4], fm[5]),  pk(fm[6], fm[7]));
            uint4 vgx = make_uint4(pk(fgx[0], fgx[1]), pk(fgx[2], fgx[3]),
                                   pk(fgx[4], fgx[5]), pk(fgx[6], fgx[7]));
            uint4 vgy = make_uint4(pk(fgy[0], fgy[1]), pk(fgy[2], fgy[3]),
                                   pk(fgy[4], fgy[5]), pk(fgy[6], fgy[7]));
            *(uint4*)&frow[8 * ((0 + half) ^ sw)] = vm;   // k 0-15  : x
            *(uint4*)&frow[8 * ((2 + half) ^ sw)] = vgx;  // k 16-31 : gx
            *(uint4*)&frow[8 * ((4 + half) ^ sw)] = vgy;  // k 32-47 : gy
        }
        const float* pd = dna + (((size_t)b * DNA_C) * HH + y) * WW + xw;
        float d0 = pd[0];
        float d1 = pd[(size_t)1 * HW];
        float d2 = pd[(size_t)2 * HW];
        float d3 = pd[(size_t)3 * HW];
        *(uint4*)&frow[8 * (6 ^ sw)] = make_uint4(pk(d0, d1), pk(d2, d3), 0u, 0u);
        *(uint4*)&frow[8 * (7 ^ sw)] = make_uint4(0u, 0u, 0u, 0u);
    }

    const int lane = tid & 63;
    const int wv   = tid >> 6;
    const int fj   = lane & 15;   // A-row / B-col / D-col
    const int fg   = lane >> 4;   // k-group (A/B), row-group (D)
    const int sfj  = fj & 7;

    // ---- weight fragments: global bf16 -> registers (L1/L2-hot, shared by all blocks) ----
    const u16* w1b = wb;             // [128][64]
    const u16* w2b = wb + 128 * 64;  // [16][128]
    bf8 a1[8][2];
    #pragma unroll
    for (int m = 0; m < 8; ++m) {
        #pragma unroll
        for (int kt = 0; kt < 2; ++kt)
            a1[m][kt] = *(const bf8*)&w1b[(16 * m + fj) * 64 + 32 * kt + 8 * fg];
    }
    bf8 a2[4];
    #pragma unroll
    for (int kt = 0; kt < 4; ++kt)
        a2[kt] = *(const bf8*)&w2b[fj * 128 + 32 * kt + 8 * fg];

    // feat writes -> reads are wave-local (wave wv reads only rows written by its own tids)
    asm volatile("s_waitcnt lgkmcnt(0)" ::: "memory");

    // ---- pre-read B fragments for g4=2,3 (rows wv*64+32..63 — about to be overlaid by h) ----
    bf8 p20, p21, p30, p31;
    {
        const int r2 = wv * 64 + 32 + fj;
        const int r3 = wv * 64 + 48 + fj;
        p20 = *(const bf8*)&feat_lds[r2 * 64 + 8 * ((0 + fg) ^ sfj)];
        p21 = *(const bf8*)&feat_lds[r2 * 64 + 8 * ((4 + fg) ^ sfj)];
        p30 = *(const bf8*)&feat_lds[r3 * 64 + 8 * ((0 + fg) ^ sfj)];
        p31 = *(const bf8*)&feat_lds[r3 * 64 + 8 * ((4 + fg) ^ sfj)];
    }
    asm volatile("s_waitcnt lgkmcnt(0)" ::: "memory");  // pre-reads land before any h write
    __builtin_amdgcn_sched_barrier(0);                  // rule #18: pin order across the asm fence

    u16* hwv = &feat_lds[wv * 4096 + 2048];   // h [16 px][128 k] over rows wv*64+32..63

    #pragma unroll
    for (int g4 = 0; g4 < 4; ++g4) {
        bf8 b0, b1;
        if (g4 == 0 || g4 == 1) {
            const int r = wv * 64 + g4 * 16 + fj;   // rows 0..31 of wave region: never overlaid
            b0 = *(const bf8*)&feat_lds[r * 64 + 8 * ((0 + fg) ^ sfj)];
            b1 = *(const bf8*)&feat_lds[r * 64 + 8 * ((4 + fg) ^ sfj)];
        } else if (g4 == 2) { b0 = p20; b1 = p21; }
        else                { b0 = p30; b1 = p31; }

        f32x4 hacc[8];
        #pragma unroll
        for (int m = 0; m < 8; ++m) {
            f32x4 z = {0.f, 0.f, 0.f, 0.f};
            z = __builtin_amdgcn_mfma_f32_16x16x32_bf16(a1[m][0], b0, z, 0, 0, 0);
            hacc[m] = __builtin_amdgcn_mfma_f32_16x16x32_bf16(a1[m][1], b1, z, 0, 0, 0);
        }

        // relu + pack; lane holds h[k=16m+4fg+r][px=fj]
        #pragma unroll
        for (int m = 0; m < 8; ++m) {
            float h0 = fmaxf(hacc[m][0], 0.f), h1 = fmaxf(hacc[m][1], 0.f);
            float h2 = fmaxf(hacc[m][2], 0.f), h3 = fmaxf(hacc[m][3], 0.f);
            *(uint2*)&hwv[fj * 128 + 8 * ((2 * m + (fg >> 1)) ^ sfj) + 4 * (fg & 1)] =
                make_uint2(pk(h0, h1), pk(h2, h3));
        }
        asm volatile("s_waitcnt lgkmcnt(0)" ::: "memory");  // wave-local h exchange

        f32x4 uacc = {0.f, 0.f, 0.f, 0.f};
        #pragma unroll
        for (int kt = 0; kt < 4; ++kt) {
            bf8 b2 = *(const bf8*)&hwv[fj * 128 + 8 * ((4 * kt + fg) ^ sfj)];
            uacc = __builtin_amdgcn_mfma_f32_16x16x32_bf16(a2[kt], b2, uacc, 0, 0, 0);
        }

        const int xo = wv * 64 + g4 * 16 + fj;
        float* po = out + (((size_t)(b * STATE + 4 * fg)) * HH + y) * WW + xo;
        #pragma unroll
        for (int rr = 0; rr < 4; ++rr)
            po[(size_t)rr * HW] = uacc[rr];
    }
}

extern "C" void kernel_launch(void* const* d_in, const int* in_sizes, int n_in,
                              void* d_out, int out_size, void* d_ws, size_t ws_size,
                              hipStream_t stream) {
    const float* x   = (const float*)d_in[0];
    const float* dna = (const float*)d_in[1];
    const float* w1  = (const float*)d_in[2];
    const float* w2  = (const float*)d_in[3];
    float* out = (float*)d_out;
    u16* wb = (u16*)d_ws;   // 10240 u16 = 20 KB

    prep_weights<<<dim3(40), dim3(256), 0, stream>>>(w1, w2, wb);

    const int B = in_sizes[0] / (STATE * HH * WW);   // 16
    update_net5<<<dim3(B * HH), dim3(256), 0, stream>>>(x, dna, wb, out);
}

// Round 6
// 175.354 us; speedup vs baseline: 1.3813x; 1.3456x over previous
//
#include <hip/hip_runtime.h>
#include <hip/hip_bf16.h>

#define STATE 16
#define DNA_C 4
#define HID   128
#define FAN1  52
#define HH    256
#define WW    256
#define HW    (HH * WW)

typedef unsigned short u16;
typedef unsigned int   u32;
typedef short bf8 __attribute__((ext_vector_type(8)));
typedef float f32x4 __attribute__((ext_vector_type(4)));

__device__ __forceinline__ u32 pk(float a, float b) {
    __hip_bfloat162 t = __float22bfloat162_rn(make_float2(a, b));  // v_cvt_pk_bf16_f32
    union { __hip_bfloat162 h; u32 u; } c; c.h = t; return c.u;
}
__device__ __forceinline__ u16 f2bf(float f) {
    union { __hip_bfloat16 h; u16 u; } c; c.h = __float2bfloat16(f); return c.u;
}

__device__ __forceinline__ void sobel1(const float* __restrict__ p,
                                       bool hl, bool hr, bool ht, bool hb,
                                       float& mc, float& gx, float& gy) {
    float tl = 0.f, tc = 0.f, tr = 0.f;
    float ml = 0.f,           mr = 0.f;
    float bl = 0.f, bc = 0.f, br = 0.f;
    mc = p[0];
    if (hl) ml = p[-1];
    if (hr) mr = p[1];
    if (ht) {
        tc = p[-WW];
        if (hl) tl = p[-WW - 1];
        if (hr) tr = p[-WW + 1];
    }
    if (hb) {
        bc = p[WW];
        if (hl) bl = p[WW - 1];
        if (hr) br = p[WW + 1];
    }
    gx = (tr - tl) + 2.f * (mr - ml) + (br - bl);
    gy = (bl + 2.f * bc + br) - (tl + 2.f * tc + tr);
}

// w1 [128][52] f32 -> bf16 [128][64] zero-padded; w2 [16][128] -> bf16 (plain k order)
__global__ void prep_weights(const float* __restrict__ w1, const float* __restrict__ w2,
                             u16* __restrict__ wb) {
    int i = blockIdx.x * 256 + threadIdx.x;   // 0..10239
    if (i < 128 * 64) {
        int r = i >> 6, k = i & 63;
        wb[i] = (k < FAN1) ? f2bf(w1[r * FAN1 + k]) : (u16)0;
    } else if (i < 128 * 64 + 16 * 128) {
        wb[i] = f2bf(w2[i - 128 * 64]);
    }
}

__global__ __launch_bounds__(256, 4) void update_net6(
    const float* __restrict__ x,    // [B,16,256,256]
    const float* __restrict__ dna,  // [B,4,256,256]
    const u16*   __restrict__ wb,   // bf16 w1 [128][64], w2 [16][128]
    float* __restrict__ out)        // [B,16,256,256]
{
    // feat: [256 px][64 k] bf16, 128B rows, 16B chunks swizzled chunk ^= px&7. 32 KB.
    // Wave wv's rows [wv*64, wv*64+64) are written and read only by wave wv.
    // h [16 px][128 k] overlays the UPPER half (rows wv*64+32..63) of the wave's region;
    // g4=2,3 B-fragments (those rows) are pre-read into registers before the first h write.
    __shared__ __align__(16) u16 feat_lds[256 * 64];

    const int tid = threadIdx.x;
    const int row = blockIdx.x;
    const int b = row >> 8;
    const int y = row & 255;

    // ---- per-thread features -> bf16 -> swizzled feat_lds[tid][*] ----
    {
        const int xw = tid;
        const bool hl = (xw > 0), hr = (xw < WW - 1);
        const bool ht = (y > 0),  hb = (y < HH - 1);
        const float* pb = x + (((size_t)b * STATE) * HH + y) * WW + xw;
        const int sw = tid & 7;
        u16* frow = &feat_lds[tid * 64];

        #pragma unroll
        for (int half = 0; half < 2; ++half) {
            float fm[8], fgx[8], fgy[8];
            #pragma unroll
            for (int c = 0; c < 8; ++c)
                sobel1(pb + (size_t)(8 * half + c) * HW, hl, hr, ht, hb,
                       fm[c], fgx[c], fgy[c]);
            uint4 vm  = make_uint4(pk(fm[0], fm[1]),  pk(fm[2], fm[3]),
                                   pk(fm[4], fm[5]),  pk(fm[6], fm[7]));
            uint4 vgx = make_uint4(pk(fgx[0], fgx[1]), pk(fgx[2], fgx[3]),
                                   pk(fgx[4], fgx[5]), pk(fgx[6], fgx[7]));
            uint4 vgy = make_uint4(pk(fgy[0], fgy[1]), pk(fgy[2], fgy[3]),
                                   pk(fgy[4], fgy[5]), pk(fgy[6], fgy[7]));
            *(uint4*)&frow[8 * ((0 + half) ^ sw)] = vm;   // k 0-15  : x
            *(uint4*)&frow[8 * ((2 + half) ^ sw)] = vgx;  // k 16-31 : gx
            *(uint4*)&frow[8 * ((4 + half) ^ sw)] = vgy;  // k 32-47 : gy
        }
        const float* pd = dna + (((size_t)b * DNA_C) * HH + y) * WW + xw;
        float d0 = pd[0];
        float d1 = pd[(size_t)1 * HW];
        float d2 = pd[(size_t)2 * HW];
        float d3 = pd[(size_t)3 * HW];
        *(uint4*)&frow[8 * (6 ^ sw)] = make_uint4(pk(d0, d1), pk(d2, d3), 0u, 0u);
        *(uint4*)&frow[8 * (7 ^ sw)] = make_uint4(0u, 0u, 0u, 0u);
    }

    const int lane = tid & 63;
    const int wv   = tid >> 6;
    const int fj   = lane & 15;   // A-row / B-col / D-col
    const int fg   = lane >> 4;   // k-group (A/B), row-group (D)
    const int sfj  = fj & 7;

    // ---- weight fragments: global bf16 -> registers (L1/L2-hot, shared by all blocks) ----
    const u16* w1b = wb;             // [128][64]
    const u16* w2b = wb + 128 * 64;  // [16][128]
    bf8 a1[8][2];
    #pragma unroll
    for (int m = 0; m < 8; ++m) {
        #pragma unroll
        for (int kt = 0; kt < 2; ++kt)
            a1[m][kt] = *(const bf8*)&w1b[(16 * m + fj) * 64 + 32 * kt + 8 * fg];
    }
    bf8 a2[4];
    #pragma unroll
    for (int kt = 0; kt < 4; ++kt)
        a2[kt] = *(const bf8*)&w2b[fj * 128 + 32 * kt + 8 * fg];

    // feat writes -> reads are wave-local (wave wv reads only rows written by its own tids)
    asm volatile("s_waitcnt lgkmcnt(0)" ::: "memory");

    // ---- pre-read B fragments for g4=2,3 (rows wv*64+32..63 — about to be overlaid by h) ----
    bf8 p20, p21, p30, p31;
    {
        const int r2 = wv * 64 + 32 + fj;
        const int r3 = wv * 64 + 48 + fj;
        p20 = *(const bf8*)&feat_lds[r2 * 64 + 8 * ((0 + fg) ^ sfj)];
        p21 = *(const bf8*)&feat_lds[r2 * 64 + 8 * ((4 + fg) ^ sfj)];
        p30 = *(const bf8*)&feat_lds[r3 * 64 + 8 * ((0 + fg) ^ sfj)];
        p31 = *(const bf8*)&feat_lds[r3 * 64 + 8 * ((4 + fg) ^ sfj)];
    }
    asm volatile("s_waitcnt lgkmcnt(0)" ::: "memory");  // pre-reads land before any h write
    __builtin_amdgcn_sched_barrier(0);                  // rule #18: pin order across the asm fence

    u16* hwv = &feat_lds[wv * 4096 + 2048];   // h [16 px][128 k] over rows wv*64+32..63

    #pragma unroll
    for (int g4 = 0; g4 < 4; ++g4) {
        bf8 b0, b1;
        if (g4 == 0 || g4 == 1) {
            const int r = wv * 64 + g4 * 16 + fj;   // rows 0..31 of wave region: never overlaid
            b0 = *(const bf8*)&feat_lds[r * 64 + 8 * ((0 + fg) ^ sfj)];
            b1 = *(const bf8*)&feat_lds[r * 64 + 8 * ((4 + fg) ^ sfj)];
        } else if (g4 == 2) { b0 = p20; b1 = p21; }
        else                { b0 = p30; b1 = p31; }

        f32x4 hacc[8];
        #pragma unroll
        for (int m = 0; m < 8; ++m) {
            f32x4 z = {0.f, 0.f, 0.f, 0.f};
            z = __builtin_amdgcn_mfma_f32_16x16x32_bf16(a1[m][0], b0, z, 0, 0, 0);
            hacc[m] = __builtin_amdgcn_mfma_f32_16x16x32_bf16(a1[m][1], b1, z, 0, 0, 0);
        }

        // relu + pack; lane holds h[k=16m+4fg+r][px=fj]
        #pragma unroll
        for (int m = 0; m < 8; ++m) {
            float h0 = fmaxf(hacc[m][0], 0.f), h1 = fmaxf(hacc[m][1], 0.f);
            float h2 = fmaxf(hacc[m][2], 0.f), h3 = fmaxf(hacc[m][3], 0.f);
            *(uint2*)&hwv[fj * 128 + 8 * ((2 * m + (fg >> 1)) ^ sfj) + 4 * (fg & 1)] =
                make_uint2(pk(h0, h1), pk(h2, h3));
        }
        asm volatile("s_waitcnt lgkmcnt(0)" ::: "memory");  // wave-local h exchange

        f32x4 uacc = {0.f, 0.f, 0.f, 0.f};
        #pragma unroll
        for (int kt = 0; kt < 4; ++kt) {
            bf8 b2 = *(const bf8*)&hwv[fj * 128 + 8 * ((4 * kt + fg) ^ sfj)];
            uacc = __builtin_amdgcn_mfma_f32_16x16x32_bf16(a2[kt], b2, uacc, 0, 0, 0);
        }

        const int xo = wv * 64 + g4 * 16 + fj;
        float* po = out + (((size_t)(b * STATE + 4 * fg)) * HH + y) * WW + xo;
        #pragma unroll
        for (int rr = 0; rr < 4; ++rr)
            po[(size_t)rr * HW] = uacc[rr];
    }
}

extern "C" void kernel_launch(void* const* d_in, const int* in_sizes, int n_in,
                              void* d_out, int out_size, void* d_ws, size_t ws_size,
                              hipStream_t stream) {
    const float* x   = (const float*)d_in[0];
    const float* dna = (const float*)d_in[1];
    const float* w1  = (const float*)d_in[2];
    const float* w2  = (const float*)d_in[3];
    float* out = (float*)d_out;
    u16* wb = (u16*)d_ws;   // 10240 u16 = 20 KB

    prep_weights<<<dim3(40), dim3(256), 0, stream>>>(w1, w2, wb);

    const int B = in_sizes[0] / (STATE * HH * WW);   // 16
    update_net6<<<dim3(B * HH), dim3(256), 0, stream>>>(x, dna, wb, out);
}

// Round 7
// 129.260 us; speedup vs baseline: 1.8739x; 1.3566x over previous
//
#include <hip/hip_runtime.h>
#include <hip/hip_bf16.h>

#define STATE 16
#define DNA_C 4
#define HID   128
#define FAN1  52
#define HH    256
#define WW    256
#define HW    (HH * WW)

typedef unsigned short u16;
typedef unsigned int   u32;
typedef short bf8 __attribute__((ext_vector_type(8)));
typedef float f32x4 __attribute__((ext_vector_type(4)));

__device__ __forceinline__ u32 pk(float a, float b) {
    __hip_bfloat162 t = __float22bfloat162_rn(make_float2(a, b));  // v_cvt_pk_bf16_f32
    union { __hip_bfloat162 h; u32 u; } c; c.h = t; return c.u;
}
__device__ __forceinline__ u16 f2bf(float f) {
    union { __hip_bfloat16 h; u16 u; } c; c.h = __float2bfloat16(f); return c.u;
}

__device__ __forceinline__ void sobel1(const float* __restrict__ p,
                                       bool hl, bool hr, bool ht, bool hb,
                                       float& mc, float& gx, float& gy) {
    float tl = 0.f, tc = 0.f, tr = 0.f;
    float ml = 0.f,           mr = 0.f;
    float bl = 0.f, bc = 0.f, br = 0.f;
    mc = p[0];
    if (hl) ml = p[-1];
    if (hr) mr = p[1];
    if (ht) {
        tc = p[-WW];
        if (hl) tl = p[-WW - 1];
        if (hr) tr = p[-WW + 1];
    }
    if (hb) {
        bc = p[WW];
        if (hl) bl = p[WW - 1];
        if (hr) br = p[WW + 1];
    }
    gx = (tr - tl) + 2.f * (mr - ml) + (br - bl);
    gy = (bl + 2.f * bc + br) - (tl + 2.f * tc + tr);
}

// w1 [128][52] f32 -> bf16 [128][64] zero-padded; w2 [16][128] -> bf16
__global__ void prep_weights(const float* __restrict__ w1, const float* __restrict__ w2,
                             u16* __restrict__ wb) {
    int i = blockIdx.x * 256 + threadIdx.x;   // 0..10239
    if (i < 128 * 64) {
        int r = i >> 6, k = i & 63;
        wb[i] = (k < FAN1) ? f2bf(w1[r * FAN1 + k]) : (u16)0;
    } else if (i < 128 * 64 + 16 * 128) {
        wb[i] = f2bf(w2[i - 128 * 64]);
    }
}

__global__ __launch_bounds__(256, 4) void update_net7(
    const float* __restrict__ x,    // [B,16,256,256]
    const float* __restrict__ dna,  // [B,4,256,256]
    const u16*   __restrict__ wb,   // bf16 w1 [128][64], w2 [16][128]
    float* __restrict__ out)        // [B,16,256,256]
{
    // feat: [256 px][64 k] bf16, 128B rows, 16B chunks swizzled chunk ^= px&7. 32 KB.
    // Wave wv owns rows [wv*64, wv*64+64) exclusively (no __syncthreads anywhere).
    // h [16 px][128 k] overlays the LOWER half (rows wv*64 .. +31):
    //   g4=0 rows are read just-in-time before the first h write,
    //   g4=1 rows are pre-read into 8 registers, g4=2,3 rows are never overlaid.
    __shared__ __align__(16) u16 feat_lds[256 * 64];

    const int tid = threadIdx.x;
    const int row = blockIdx.x;
    const int b = row >> 8;
    const int y = row & 255;

    // ---- per-thread features -> bf16 -> swizzled feat_lds[tid][*] (quarters of 4 ch) ----
    {
        const int xw = tid;
        const bool hl = (xw > 0), hr = (xw < WW - 1);
        const bool ht = (y > 0),  hb = (y < HH - 1);
        const float* pb = x + (((size_t)b * STATE) * HH + y) * WW + xw;
        const int sw = tid & 7;
        u16* frow = &feat_lds[tid * 64];

        #pragma unroll
        for (int q = 0; q < 4; ++q) {
            float fm[4], fgx[4], fgy[4];
            #pragma unroll
            for (int c = 0; c < 4; ++c)
                sobel1(pb + (size_t)(4 * q + c) * HW, hl, hr, ht, hb,
                       fm[c], fgx[c], fgy[c]);
            const int hc = q >> 1, ho = 4 * (q & 1);
            *(uint2*)&frow[8 * ((0 + hc) ^ sw) + ho] = make_uint2(pk(fm[0],  fm[1]),  pk(fm[2],  fm[3]));
            *(uint2*)&frow[8 * ((2 + hc) ^ sw) + ho] = make_uint2(pk(fgx[0], fgx[1]), pk(fgx[2], fgx[3]));
            *(uint2*)&frow[8 * ((4 + hc) ^ sw) + ho] = make_uint2(pk(fgy[0], fgy[1]), pk(fgy[2], fgy[3]));
        }
        const float* pd = dna + (((size_t)b * DNA_C) * HH + y) * WW + xw;
        float d0 = pd[0];
        float d1 = pd[(size_t)1 * HW];
        float d2 = pd[(size_t)2 * HW];
        float d3 = pd[(size_t)3 * HW];
        *(uint4*)&frow[8 * (6 ^ sw)] = make_uint4(pk(d0, d1), pk(d2, d3), 0u, 0u);
        *(uint4*)&frow[8 * (7 ^ sw)] = make_uint4(0u, 0u, 0u, 0u);
    }

    const int lane = tid & 63;
    const int wv   = tid >> 6;
    const int fj   = lane & 15;   // A-row / B-col / D-col
    const int fg   = lane >> 4;   // k-group (A/B), row-group (D)
    const int sfj  = fj & 7;

    // ---- weight fragments: global bf16 -> registers (L1/L2-hot, shared by all blocks) ----
    const u16* w1b = wb;             // [128][64]
    const u16* w2b = wb + 128 * 64;  // [16][128]
    bf8 a1[8][2];
    #pragma unroll
    for (int m = 0; m < 8; ++m) {
        #pragma unroll
        for (int kt = 0; kt < 2; ++kt)
            a1[m][kt] = *(const bf8*)&w1b[(16 * m + fj) * 64 + 32 * kt + 8 * fg];
    }
    bf8 a2[4];
    #pragma unroll
    for (int kt = 0; kt < 4; ++kt)
        a2[kt] = *(const bf8*)&w2b[fj * 128 + 32 * kt + 8 * fg];

    // feat writes -> reads are wave-local (wave wv reads only rows written by its own tids)
    asm volatile("s_waitcnt lgkmcnt(0)" ::: "memory");

    // ---- B-frags: g4=0 just-in-time, g4=1 pre-read (its rows are overlaid by g4=0's h) ----
    bf8 b00, b01, p10, p11;
    {
        const int r0 = wv * 64 +  0 + fj;
        const int r1 = wv * 64 + 16 + fj;
        b00 = *(const bf8*)&feat_lds[r0 * 64 + 8 * ((0 + fg) ^ sfj)];
        b01 = *(const bf8*)&feat_lds[r0 * 64 + 8 * ((4 + fg) ^ sfj)];
        p10 = *(const bf8*)&feat_lds[r1 * 64 + 8 * ((0 + fg) ^ sfj)];
        p11 = *(const bf8*)&feat_lds[r1 * 64 + 8 * ((4 + fg) ^ sfj)];
    }
    asm volatile("s_waitcnt lgkmcnt(0)" ::: "memory");  // pre-reads land before any h write
    __builtin_amdgcn_sched_barrier(0);                  // rule #18: pin order across the fence

    u16* hwv = &feat_lds[wv * 4096];   // h [16 px][128 k] over rows wv*64 .. +31

    #pragma unroll
    for (int g4 = 0; g4 < 4; ++g4) {
        bf8 b0, b1;
        if (g4 == 0)      { b0 = b00; b1 = b01; }
        else if (g4 == 1) { b0 = p10; b1 = p11; }
        else {
            const int r = wv * 64 + g4 * 16 + fj;   // rows +32..63: never overlaid
            b0 = *(const bf8*)&feat_lds[r * 64 + 8 * ((0 + fg) ^ sfj)];
            b1 = *(const bf8*)&feat_lds[r * 64 + 8 * ((4 + fg) ^ sfj)];
        }

        // ---- layer 1 in two m-halves (accumulator 16 regs instead of 32) ----
        #pragma unroll
        for (int mh = 0; mh < 2; ++mh) {
            f32x4 hc[4];
            #pragma unroll
            for (int mm = 0; mm < 4; ++mm) {
                const int m = mh * 4 + mm;
                f32x4 z = {0.f, 0.f, 0.f, 0.f};
                z = __builtin_amdgcn_mfma_f32_16x16x32_bf16(a1[m][0], b0, z, 0, 0, 0);
                hc[mm] = __builtin_amdgcn_mfma_f32_16x16x32_bf16(a1[m][1], b1, z, 0, 0, 0);
            }
            #pragma unroll
            for (int mm = 0; mm < 4; ++mm) {
                const int m = mh * 4 + mm;
                float h0 = fmaxf(hc[mm][0], 0.f), h1 = fmaxf(hc[mm][1], 0.f);
                float h2 = fmaxf(hc[mm][2], 0.f), h3 = fmaxf(hc[mm][3], 0.f);
                *(uint2*)&hwv[fj * 128 + 8 * ((2 * m + (fg >> 1)) ^ sfj) + 4 * (fg & 1)] =
                    make_uint2(pk(h0, h1), pk(h2, h3));
            }
        }
        asm volatile("s_waitcnt lgkmcnt(0)" ::: "memory");  // wave-local h exchange

        f32x4 uacc = {0.f, 0.f, 0.f, 0.f};
        #pragma unroll
        for (int kt = 0; kt < 4; ++kt) {
            bf8 b2 = *(const bf8*)&hwv[fj * 128 + 8 * ((4 * kt + fg) ^ sfj)];
            uacc = __builtin_amdgcn_mfma_f32_16x16x32_bf16(a2[kt], b2, uacc, 0, 0, 0);
        }

        const int xo = wv * 64 + g4 * 16 + fj;
        float* po = out + (((size_t)(b * STATE + 4 * fg)) * HH + y) * WW + xo;
        #pragma unroll
        for (int rr = 0; rr < 4; ++rr)
            po[(size_t)rr * HW] = uacc[rr];
    }
}

extern "C" void kernel_launch(void* const* d_in, const int* in_sizes, int n_in,
                              void* d_out, int out_size, void* d_ws, size_t ws_size,
                              hipStream_t stream) {
    const float* x   = (const float*)d_in[0];
    const float* dna = (const float*)d_in[1];
    const float* w1  = (const float*)d_in[2];
    const float* w2  = (const float*)d_in[3];
    float* out = (float*)d_out;
    u16* wb = (u16*)d_ws;   // 10240 u16 = 20 KB

    prep_weights<<<dim3(40), dim3(256), 0, stream>>>(w1, w2, wb);

    const int B = in_sizes[0] / (STATE * HH * WW);   // 16
    update_net7<<<dim3(B * HH), dim3(256), 0, stream>>>(x, dna, wb, out);
}

// Round 8
// 89.181 us; speedup vs baseline: 2.7160x; 1.4494x over previous
//
#include <hip/hip_runtime.h>
#include <hip/hip_bf16.h>

#define STATE 16
#define DNA_C 4
#define HID   128
#define FAN1  52
#define HH    256
#define WW    256
#define HW    (HH * WW)

typedef unsigned short u16;
typedef unsigned int   u32;
typedef short bf8 __attribute__((ext_vector_type(8)));
typedef float f32x4 __attribute__((ext_vector_type(4)));

__device__ __forceinline__ u32 pk(float a, float b) {
    __hip_bfloat162 t = __float22bfloat162_rn(make_float2(a, b));  // v_cvt_pk_bf16_f32
    union { __hip_bfloat162 h; u32 u; } c; c.h = t; return c.u;
}
__device__ __forceinline__ u16 f2bf(float f) {
    union { __hip_bfloat16 h; u16 u; } c; c.h = __float2bfloat16(f); return c.u;
}

__device__ __forceinline__ void sobel1(const float* __restrict__ p,
                                       bool hl, bool hr, bool ht, bool hb,
                                       float& mc, float& gx, float& gy) {
    float tl = 0.f, tc = 0.f, tr = 0.f;
    float ml = 0.f,           mr = 0.f;
    float bl = 0.f, bc = 0.f, br = 0.f;
    mc = p[0];
    if (hl) ml = p[-1];
    if (hr) mr = p[1];
    if (ht) {
        tc = p[-WW];
        if (hl) tl = p[-WW - 1];
        if (hr) tr = p[-WW + 1];
    }
    if (hb) {
        bc = p[WW];
        if (hl) bl = p[WW - 1];
        if (hr) br = p[WW + 1];
    }
    gx = (tr - tl) + 2.f * (mr - ml) + (br - bl);
    gy = (bl + 2.f * bc + br) - (tl + 2.f * tc + tr);
}

// w1 [128][52] f32 -> bf16 [128][64] zero-padded; w2 [16][128] -> bf16
__global__ void prep_weights(const float* __restrict__ w1, const float* __restrict__ w2,
                             u16* __restrict__ wb) {
    int i = blockIdx.x * 256 + threadIdx.x;   // 0..10239
    if (i < 128 * 64) {
        int r = i >> 6, k = i & 63;
        wb[i] = (k < FAN1) ? f2bf(w1[r * FAN1 + k]) : (u16)0;
    } else if (i < 128 * 64 + 16 * 128) {
        wb[i] = f2bf(w2[i - 128 * 64]);
    }
}

__global__ __launch_bounds__(256, 3) void update_net8(
    const float* __restrict__ x,    // [B,16,256,256]
    const float* __restrict__ dna,  // [B,4,256,256]
    const u16*   __restrict__ wb,   // bf16 w1 [128][64], w2 [16][128]
    float* __restrict__ out)        // [B,16,256,256]
{
    // feat: [256 px][64 k] bf16, 128B rows, 16B chunks swizzled chunk ^= px&7. 32 KB.
    // Wave wv owns rows [wv*64, wv*64+64) exclusively (no __syncthreads anywhere).
    // h [16 px][128 k] overlays the LOWER half (rows wv*64 .. +31):
    //   g4=0 rows are read just-in-time before the first h write,
    //   g4=1 rows are pre-read into 8 registers, g4=2,3 rows are never overlaid.
    __shared__ __align__(16) u16 feat_lds[256 * 64];

    const int tid = threadIdx.x;
    const int row = blockIdx.x;
    const int b = row >> 8;
    const int y = row & 255;

    // ---- per-thread features -> bf16 -> swizzled feat_lds[tid][*] (quarters of 4 ch) ----
    {
        const int xw = tid;
        const bool hl = (xw > 0), hr = (xw < WW - 1);
        const bool ht = (y > 0),  hb = (y < HH - 1);
        const float* pb = x + (((size_t)b * STATE) * HH + y) * WW + xw;
        const int sw = tid & 7;
        u16* frow = &feat_lds[tid * 64];

        #pragma unroll
        for (int q = 0; q < 4; ++q) {
            float fm[4], fgx[4], fgy[4];
            #pragma unroll
            for (int c = 0; c < 4; ++c)
                sobel1(pb + (size_t)(4 * q + c) * HW, hl, hr, ht, hb,
                       fm[c], fgx[c], fgy[c]);
            const int hc = q >> 1, ho = 4 * (q & 1);
            *(uint2*)&frow[8 * ((0 + hc) ^ sw) + ho] = make_uint2(pk(fm[0],  fm[1]),  pk(fm[2],  fm[3]));
            *(uint2*)&frow[8 * ((2 + hc) ^ sw) + ho] = make_uint2(pk(fgx[0], fgx[1]), pk(fgx[2], fgx[3]));
            *(uint2*)&frow[8 * ((4 + hc) ^ sw) + ho] = make_uint2(pk(fgy[0], fgy[1]), pk(fgy[2], fgy[3]));
        }
        const float* pd = dna + (((size_t)b * DNA_C) * HH + y) * WW + xw;
        float d0 = pd[0];
        float d1 = pd[(size_t)1 * HW];
        float d2 = pd[(size_t)2 * HW];
        float d3 = pd[(size_t)3 * HW];
        *(uint4*)&frow[8 * (6 ^ sw)] = make_uint4(pk(d0, d1), pk(d2, d3), 0u, 0u);
        *(uint4*)&frow[8 * (7 ^ sw)] = make_uint4(0u, 0u, 0u, 0u);
    }

    const int lane = tid & 63;
    const int wv   = tid >> 6;
    const int fj   = lane & 15;   // A-row / B-col / D-col
    const int fg   = lane >> 4;   // k-group (A/B), row-group (D)
    const int sfj  = fj & 7;

    // ---- weight fragments: global bf16 -> registers (L1/L2-hot, shared by all blocks) ----
    const u16* w1b = wb;             // [128][64]
    const u16* w2b = wb + 128 * 64;  // [16][128]
    bf8 a1[8][2];
    #pragma unroll
    for (int m = 0; m < 8; ++m) {
        #pragma unroll
        for (int kt = 0; kt < 2; ++kt)
            a1[m][kt] = *(const bf8*)&w1b[(16 * m + fj) * 64 + 32 * kt + 8 * fg];
    }
    bf8 a2[4];
    #pragma unroll
    for (int kt = 0; kt < 4; ++kt)
        a2[kt] = *(const bf8*)&w2b[fj * 128 + 32 * kt + 8 * fg];

    // feat writes -> reads are wave-local (wave wv reads only rows written by its own tids)
    asm volatile("s_waitcnt lgkmcnt(0)" ::: "memory");

    // ---- B-frags: g4=0 just-in-time, g4=1 pre-read (its rows are overlaid by g4=0's h) ----
    bf8 b00, b01, p10, p11;
    {
        const int r0 = wv * 64 +  0 + fj;
        const int r1 = wv * 64 + 16 + fj;
        b00 = *(const bf8*)&feat_lds[r0 * 64 + 8 * ((0 + fg) ^ sfj)];
        b01 = *(const bf8*)&feat_lds[r0 * 64 + 8 * ((4 + fg) ^ sfj)];
        p10 = *(const bf8*)&feat_lds[r1 * 64 + 8 * ((0 + fg) ^ sfj)];
        p11 = *(const bf8*)&feat_lds[r1 * 64 + 8 * ((4 + fg) ^ sfj)];
    }
    asm volatile("s_waitcnt lgkmcnt(0)" ::: "memory");  // pre-reads land before any h write
    __builtin_amdgcn_sched_barrier(0);                  // rule #18: pin order across the fence

    u16* hwv = &feat_lds[wv * 4096];   // h [16 px][128 k] over rows wv*64 .. +31

    #pragma unroll
    for (int g4 = 0; g4 < 4; ++g4) {
        bf8 b0, b1;
        if (g4 == 0)      { b0 = b00; b1 = b01; }
        else if (g4 == 1) { b0 = p10; b1 = p11; }
        else {
            const int r = wv * 64 + g4 * 16 + fj;   // rows +32..63: never overlaid
            b0 = *(const bf8*)&feat_lds[r * 64 + 8 * ((0 + fg) ^ sfj)];
            b1 = *(const bf8*)&feat_lds[r * 64 + 8 * ((4 + fg) ^ sfj)];
        }

        // ---- layer 1 in two m-halves (accumulator 16 regs instead of 32) ----
        #pragma unroll
        for (int mh = 0; mh < 2; ++mh) {
            f32x4 hc[4];
            #pragma unroll
            for (int mm = 0; mm < 4; ++mm) {
                const int m = mh * 4 + mm;
                f32x4 z = {0.f, 0.f, 0.f, 0.f};
                z = __builtin_amdgcn_mfma_f32_16x16x32_bf16(a1[m][0], b0, z, 0, 0, 0);
                hc[mm] = __builtin_amdgcn_mfma_f32_16x16x32_bf16(a1[m][1], b1, z, 0, 0, 0);
            }
            #pragma unroll
            for (int mm = 0; mm < 4; ++mm) {
                const int m = mh * 4 + mm;
                float h0 = fmaxf(hc[mm][0], 0.f), h1 = fmaxf(hc[mm][1], 0.f);
                float h2 = fmaxf(hc[mm][2], 0.f), h3 = fmaxf(hc[mm][3], 0.f);
                *(uint2*)&hwv[fj * 128 + 8 * ((2 * m + (fg >> 1)) ^ sfj) + 4 * (fg & 1)] =
                    make_uint2(pk(h0, h1), pk(h2, h3));
            }
        }
        asm volatile("s_waitcnt lgkmcnt(0)" ::: "memory");  // wave-local h exchange

        f32x4 uacc = {0.f, 0.f, 0.f, 0.f};
        #pragma unroll
        for (int kt = 0; kt < 4; ++kt) {
            bf8 b2 = *(const bf8*)&hwv[fj * 128 + 8 * ((4 * kt + fg) ^ sfj)];
            uacc = __builtin_amdgcn_mfma_f32_16x16x32_bf16(a2[kt], b2, uacc, 0, 0, 0);
        }

        const int xo = wv * 64 + g4 * 16 + fj;
        float* po = out + (((size_t)(b * STATE + 4 * fg)) * HH + y) * WW + xo;
        #pragma unroll
        for (int rr = 0; rr < 4; ++rr)
            po[(size_t)rr * HW] = uacc[rr];
    }
}

extern "C" void kernel_launch(void* const* d_in, const int* in_sizes, int n_in,
                              void* d_out, int out_size, void* d_ws, size_t ws_size,
                              hipStream_t stream) {
    const float* x   = (const float*)d_in[0];
    const float* dna = (const float*)d_in[1];
    const float* w1  = (const float*)d_in[2];
    const float* w2  = (const float*)d_in[3];
    float* out = (float*)d_out;
    u16* wb = (u16*)d_ws;   // 10240 u16 = 20 KB

    prep_weights<<<dim3(40), dim3(256), 0, stream>>>(w1, w2, wb);

    const int B = in_sizes[0] / (STATE * HH * WW);   // 16
    update_net8<<<dim3(B * HH), dim3(256), 0, stream>>>(x, dna, wb, out);
}

// Round 9
// 75.250 us; speedup vs baseline: 3.2188x; 1.1851x over previous
//
#include <hip/hip_runtime.h>
#include <hip/hip_bf16.h>

#define STATE 16
#define DNA_C 4
#define HID   128
#define FAN1  52
#define HH    256
#define WW    256
#define HW    (HH * WW)

typedef unsigned short u16;
typedef unsigned int   u32;
typedef short bf8 __attribute__((ext_vector_type(8)));
typedef float f32x4 __attribute__((ext_vector_type(4)));

__device__ __forceinline__ u32 pk(float a, float b) {
    __hip_bfloat162 t = __float22bfloat162_rn(make_float2(a, b));  // v_cvt_pk_bf16_f32
    union { __hip_bfloat162 h; u32 u; } c; c.h = t; return c.u;
}
__device__ __forceinline__ u16 f2bf(float f) {
    union { __hip_bfloat16 h; u16 u; } c; c.h = __float2bfloat16(f); return c.u;
}

// w1 [128][52] f32 -> bf16 [128][64] with k-permutation baked in:
// knew = 16w + t : t0-3 = x ch 4w+t, t4-7 = gx ch 4w+(t-4), t8-11 = gy ch 4w+(t-8),
//                  t12-15 = dna (w==0) else zero-pad.   w2 [16][128] -> bf16 plain.
__global__ void prep_weights(const float* __restrict__ w1, const float* __restrict__ w2,
                             u16* __restrict__ wb) {
    int i = blockIdx.x * 256 + threadIdx.x;   // 0..10239
    if (i < 128 * 64) {
        int r = i >> 6, knew = i & 63;
        int w = knew >> 4, t = knew & 15;
        float v = 0.f;
        if (t < 4)        v = w1[r * FAN1 + 4 * w + t];
        else if (t < 8)   v = w1[r * FAN1 + 16 + 4 * w + (t - 4)];
        else if (t < 12)  v = w1[r * FAN1 + 32 + 4 * w + (t - 8)];
        else if (w == 0)  v = w1[r * FAN1 + 48 + (t - 12)];
        wb[i] = f2bf(v);
    } else if (i < 128 * 64 + 16 * 128) {
        wb[i] = f2bf(w2[i - 128 * 64]);
    }
}

__global__ __launch_bounds__(256, 3) void update_net9(
    const float* __restrict__ x,    // [B,16,256,256]
    const float* __restrict__ dna,  // [B,4,256,256]
    const u16*   __restrict__ wb,   // permuted bf16 w1 [128][64], w2 [16][128]
    float* __restrict__ out)        // [B,16,256,256]
{
    // feat: [256 px][64 k] bf16, 128B rows, 16B chunks swizzled chunk ^= (px>>2)&7. 32 KB.
    // Feature phase is cross-wave (wave wv writes chunks 2wv,2wv+1 of ALL rows) -> one barrier.
    // After the barrier wave wv owns rows [wv*64, wv*64+64); h [16 px][128 k] overlays the
    // LOWER half (rows wv*64..+31): g4=0 read JIT, g4=1 pre-read, g4=2,3 never overlaid.
    __shared__ __align__(16) u16 feat_lds[256 * 64];

    const int tid  = threadIdx.x;
    const int lane = tid & 63;
    const int wv   = tid >> 6;
    const int row  = blockIdx.x;
    const int b    = row >> 8;
    const int y    = row & 255;
    const bool ht  = (y > 0), hb = (y < HH - 1);   // block-uniform

    // ---- feature phase: wave wv -> channels 4wv..4wv+3, full row, 4 px/lane ----
    {
        const int px0 = lane * 4;
        const float* base = x + (((size_t)(b * STATE + 4 * wv)) * HH + y) * WW + px0;

        f32x4 xm[4], gx[4], gy[4];
        #pragma unroll
        for (int c = 0; c < 4; ++c) {
            const float* p = base + (size_t)c * HW;
            f32x4 m4 = *(const f32x4*)p;
            f32x4 t4 = {0.f,0.f,0.f,0.f}, b4 = {0.f,0.f,0.f,0.f};
            if (ht) t4 = *(const f32x4*)(p - WW);
            if (hb) b4 = *(const f32x4*)(p + WW);
            f32x4 cs, d;
            #pragma unroll
            for (int i = 0; i < 4; ++i) {
                cs[i] = fmaf(2.f, m4[i], t4[i] + b4[i]);   // colsum t+2m+b
                d[i]  = b4[i] - t4[i];
            }
            float csL = __shfl_up(cs[3], 1);
            float csR = __shfl_down(cs[0], 1);
            float dL  = __shfl_up(d[3], 1);
            float dR  = __shfl_down(d[0], 1);
            if (lane == 0)  { csL = 0.f; dL = 0.f; }       // image left border (zero pad)
            if (lane == 63) { csR = 0.f; dR = 0.f; }       // image right border
            xm[c] = m4;
            gx[c][0] = cs[1] - csL;   gx[c][1] = cs[2] - cs[0];
            gx[c][2] = cs[3] - cs[1]; gx[c][3] = csR - cs[2];
            gy[c][0] = fmaf(2.f, d[0], dL + d[1]);
            gy[c][1] = fmaf(2.f, d[1], d[0] + d[2]);
            gy[c][2] = fmaf(2.f, d[2], d[1] + d[3]);
            gy[c][3] = fmaf(2.f, d[3], d[2] + dR);
        }
        f32x4 dn[4] = {{0,0,0,0},{0,0,0,0},{0,0,0,0},{0,0,0,0}};
        if (wv == 0) {
            #pragma unroll
            for (int dc = 0; dc < 4; ++dc)
                dn[dc] = *(const f32x4*)(dna + (((size_t)(b * DNA_C + dc)) * HH + y) * WW + px0);
        }
        const int s = lane & 7;   // (px>>2)&7 for all 4 px of this lane
        #pragma unroll
        for (int i = 0; i < 4; ++i) {
            u16* rowp = &feat_lds[(px0 + i) * 64];
            uint4 c0 = make_uint4(pk(xm[0][i], xm[1][i]), pk(xm[2][i], xm[3][i]),
                                  pk(gx[0][i], gx[1][i]), pk(gx[2][i], gx[3][i]));
            uint4 c1 = make_uint4(pk(gy[0][i], gy[1][i]), pk(gy[2][i], gy[3][i]),
                                  pk(dn[0][i], dn[1][i]), pk(dn[2][i], dn[3][i]));
            *(uint4*)&rowp[8 * ((2 * wv)     ^ s)] = c0;   // knew 16wv..+7  : x | gx
            *(uint4*)&rowp[8 * ((2 * wv + 1) ^ s)] = c1;   // knew 16wv+8..15: gy | dna/pad
        }
    }

    const int fj  = lane & 15;   // A-row / B-col / D-col
    const int fg  = lane >> 4;   // k-group (A/B), row-group (D)
    const int sfj = fj & 7;      // h-buffer swizzle
    const int f4  = fj >> 2;     // feat read swizzle base: sg(g4) = (4*g4 + f4) & 7

    // ---- weight fragments: global bf16 -> registers (issued before barrier) ----
    const u16* w1b = wb;             // [128][64] (k-permuted)
    const u16* w2b = wb + 128 * 64;  // [16][128]
    bf8 a1[8][2];
    #pragma unroll
    for (int m = 0; m < 8; ++m) {
        #pragma unroll
        for (int kt = 0; kt < 2; ++kt)
            a1[m][kt] = *(const bf8*)&w1b[(16 * m + fj) * 64 + 32 * kt + 8 * fg];
    }
    bf8 a2[4];
    #pragma unroll
    for (int kt = 0; kt < 4; ++kt)
        a2[kt] = *(const bf8*)&w2b[fj * 128 + 32 * kt + 8 * fg];

    __syncthreads();   // feature phase is cross-wave

    // ---- B-frags: g4=0 just-in-time, g4=1 pre-read (rows overlaid by g4=0's h) ----
    bf8 b00, b01, p10, p11;
    {
        const int r0 = wv * 64 +  0 + fj;   const int s0 = f4;            // (0*4+f4)&7
        const int r1 = wv * 64 + 16 + fj;   const int s1 = (4 + f4) & 7;  // (1*4+f4)&7
        b00 = *(const bf8*)&feat_lds[r0 * 64 + 8 * ((0 + fg) ^ s0)];
        b01 = *(const bf8*)&feat_lds[r0 * 64 + 8 * ((4 + fg) ^ s0)];
        p10 = *(const bf8*)&feat_lds[r1 * 64 + 8 * ((0 + fg) ^ s1)];
        p11 = *(const bf8*)&feat_lds[r1 * 64 + 8 * ((4 + fg) ^ s1)];
    }
    asm volatile("s_waitcnt lgkmcnt(0)" ::: "memory");  // pre-reads land before any h write
    __builtin_amdgcn_sched_barrier(0);                  // rule #18: pin order across the fence

    u16* hwv = &feat_lds[wv * 4096];   // h [16 px][128 k] over rows wv*64 .. +31

    #pragma unroll
    for (int g4 = 0; g4 < 4; ++g4) {
        bf8 b0, b1;
        if (g4 == 0)      { b0 = b00; b1 = b01; }
        else if (g4 == 1) { b0 = p10; b1 = p11; }
        else {
            const int r  = wv * 64 + g4 * 16 + fj;     // rows +32..63: never overlaid
            const int sg = (4 * g4 + f4) & 7;
            b0 = *(const bf8*)&feat_lds[r * 64 + 8 * ((0 + fg) ^ sg)];
            b1 = *(const bf8*)&feat_lds[r * 64 + 8 * ((4 + fg) ^ sg)];
        }

        // ---- layer 1 in two m-halves (16-reg accumulator) ----
        #pragma unroll
        for (int mh = 0; mh < 2; ++mh) {
            f32x4 hc[4];
            #pragma unroll
            for (int mm = 0; mm < 4; ++mm) {
                const int m = mh * 4 + mm;
                f32x4 z = {0.f, 0.f, 0.f, 0.f};
                z = __builtin_amdgcn_mfma_f32_16x16x32_bf16(a1[m][0], b0, z, 0, 0, 0);
                hc[mm] = __builtin_amdgcn_mfma_f32_16x16x32_bf16(a1[m][1], b1, z, 0, 0, 0);
            }
            #pragma unroll
            for (int mm = 0; mm < 4; ++mm) {
                const int m = mh * 4 + mm;
                float h0 = fmaxf(hc[mm][0], 0.f), h1 = fmaxf(hc[mm][1], 0.f);
                float h2 = fmaxf(hc[mm][2], 0.f), h3 = fmaxf(hc[mm][3], 0.f);
                *(uint2*)&hwv[fj * 128 + 8 * ((2 * m + (fg >> 1)) ^ sfj) + 4 * (fg & 1)] =
                    make_uint2(pk(h0, h1), pk(h2, h3));
            }
        }
        asm volatile("s_waitcnt lgkmcnt(0)" ::: "memory");  // wave-local h exchange

        f32x4 uacc = {0.f, 0.f, 0.f, 0.f};
        #pragma unroll
        for (int kt = 0; kt < 4; ++kt) {
            bf8 b2 = *(const bf8*)&hwv[fj * 128 + 8 * ((4 * kt + fg) ^ sfj)];
            uacc = __builtin_amdgcn_mfma_f32_16x16x32_bf16(a2[kt], b2, uacc, 0, 0, 0);
        }

        const int xo = wv * 64 + g4 * 16 + fj;
        float* po = out + (((size_t)(b * STATE + 4 * fg)) * HH + y) * WW + xo;
        #pragma unroll
        for (int rr = 0; rr < 4; ++rr)
            po[(size_t)rr * HW] = uacc[rr];
    }
}

extern "C" void kernel_launch(void* const* d_in, const int* in_sizes, int n_in,
                              void* d_out, int out_size, void* d_ws, size_t ws_size,
                              hipStream_t stream) {
    const float* x   = (const float*)d_in[0];
    const float* dna = (const float*)d_in[1];
    const float* w1  = (const float*)d_in[2];
    const float* w2  = (const float*)d_in[3];
    float* out = (float*)d_out;
    u16* wb = (u16*)d_ws;   // 10240 u16 = 20 KB

    prep_weights<<<dim3(40), dim3(256), 0, stream>>>(w1, w2, wb);

    const int B = in_sizes[0] / (STATE * HH * WW);   // 16
    update_net9<<<dim3(B * HH), dim3(256), 0, stream>>>(x, dna, wb, out);
}

// Round 10
// 74.246 us; speedup vs baseline: 3.2623x; 1.0135x over previous
//
#include <hip/hip_runtime.h>
#include <hip/hip_bf16.h>

#define STATE 16
#define DNA_C 4
#define HID   128
#define FAN1  52
#define HH    256
#define WW    256
#define HW    (HH * WW)

typedef unsigned short u16;
typedef unsigned int   u32;
typedef short bf8 __attribute__((ext_vector_type(8)));
typedef float f32x4 __attribute__((ext_vector_type(4)));

__device__ __forceinline__ u32 pk(float a, float b) {
    __hip_bfloat162 t = __float22bfloat162_rn(make_float2(a, b));  // v_cvt_pk_bf16_f32
    union { __hip_bfloat162 h; u32 u; } c; c.h = t; return c.u;
}
__device__ __forceinline__ u16 f2bf(float f) {
    union { __hip_bfloat16 h; u16 u; } c; c.h = __float2bfloat16(f); return c.u;
}

// w1 [128][52] f32 -> bf16 [128][64] with k-permutation baked in:
// knew = 16w + t : t0-3 = x ch 4w+t, t4-7 = gx ch 4w+(t-4), t8-11 = gy ch 4w+(t-8),
//                  t12-15 = dna (w==0) else zero-pad.   w2 [16][128] -> bf16 plain.
__global__ void prep_weights(const float* __restrict__ w1, const float* __restrict__ w2,
                             u16* __restrict__ wb) {
    int i = blockIdx.x * 256 + threadIdx.x;   // 0..10239
    if (i < 128 * 64) {
        int r = i >> 6, knew = i & 63;
        int w = knew >> 4, t = knew & 15;
        float v = 0.f;
        if (t < 4)        v = w1[r * FAN1 + 4 * w + t];
        else if (t < 8)   v = w1[r * FAN1 + 16 + 4 * w + (t - 4)];
        else if (t < 12)  v = w1[r * FAN1 + 32 + 4 * w + (t - 8)];
        else if (w == 0)  v = w1[r * FAN1 + 48 + (t - 12)];
        wb[i] = f2bf(v);
    } else if (i < 128 * 64 + 16 * 128) {
        wb[i] = f2bf(w2[i - 128 * 64]);
    }
}

__global__ __launch_bounds__(256, 3) void update_net10(
    const float* __restrict__ x,    // [B,16,256,256]
    const float* __restrict__ dna,  // [B,4,256,256]
    const u16*   __restrict__ wb,   // permuted bf16 w1 [128][64], w2 [16][128]
    float* __restrict__ out)        // [B,16,256,256]
{
    // feat: [256 px][64 k] bf16, 128B rows, 16B chunks swizzled chunk ^= (px>>2)&7. 32 KB.
    // Feature phase is cross-wave (wave wv writes chunks 2wv,2wv+1 of ALL rows) -> one barrier.
    // After the barrier wave wv owns rows [wv*64, wv*64+64); h [16 px][128 k] overlays the
    // LOWER half (rows wv*64..+31): g4=0 read JIT, g4=1 pre-read, g4=2,3 never overlaid.
    // NO manual lgkmcnt fences: per-wave DS ops are in-order; the compiler preserves
    // program order through the feat_lds may-alias and uses counted lgkmcnt(N) waits,
    // letting g4 iteration n+1's layer-1 overlap iteration n's layer-2.
    __shared__ __align__(16) u16 feat_lds[256 * 64];

    const int tid  = threadIdx.x;
    const int lane = tid & 63;
    const int wv   = tid >> 6;
    const int row  = blockIdx.x;
    const int b    = row >> 8;
    const int y    = row & 255;
    const bool ht  = (y > 0), hb = (y < HH - 1);   // block-uniform

    // ---- feature phase: wave wv -> channels 4wv..4wv+3, full row, 4 px/lane ----
    {
        const int px0 = lane * 4;
        const float* base = x + (((size_t)(b * STATE + 4 * wv)) * HH + y) * WW + px0;

        f32x4 xm[4], gx[4], gy[4];
        #pragma unroll
        for (int c = 0; c < 4; ++c) {
            const float* p = base + (size_t)c * HW;
            f32x4 m4 = *(const f32x4*)p;
            f32x4 t4 = {0.f,0.f,0.f,0.f}, b4 = {0.f,0.f,0.f,0.f};
            if (ht) t4 = *(const f32x4*)(p - WW);
            if (hb) b4 = *(const f32x4*)(p + WW);
            f32x4 cs, d;
            #pragma unroll
            for (int i = 0; i < 4; ++i) {
                cs[i] = fmaf(2.f, m4[i], t4[i] + b4[i]);   // colsum t+2m+b
                d[i]  = b4[i] - t4[i];
            }
            float csL = __shfl_up(cs[3], 1);
            float csR = __shfl_down(cs[0], 1);
            float dL  = __shfl_up(d[3], 1);
            float dR  = __shfl_down(d[0], 1);
            if (lane == 0)  { csL = 0.f; dL = 0.f; }       // image left border (zero pad)
            if (lane == 63) { csR = 0.f; dR = 0.f; }       // image right border
            xm[c] = m4;
            gx[c][0] = cs[1] - csL;   gx[c][1] = cs[2] - cs[0];
            gx[c][2] = cs[3] - cs[1]; gx[c][3] = csR - cs[2];
            gy[c][0] = fmaf(2.f, d[0], dL + d[1]);
            gy[c][1] = fmaf(2.f, d[1], d[0] + d[2]);
            gy[c][2] = fmaf(2.f, d[2], d[1] + d[3]);
            gy[c][3] = fmaf(2.f, d[3], d[2] + dR);
        }
        f32x4 dn[4] = {{0,0,0,0},{0,0,0,0},{0,0,0,0},{0,0,0,0}};
        if (wv == 0) {
            #pragma unroll
            for (int dc = 0; dc < 4; ++dc)
                dn[dc] = *(const f32x4*)(dna + (((size_t)(b * DNA_C + dc)) * HH + y) * WW + px0);
        }
        const int s = lane & 7;   // (px>>2)&7 for all 4 px of this lane
        #pragma unroll
        for (int i = 0; i < 4; ++i) {
            u16* rowp = &feat_lds[(px0 + i) * 64];
            uint4 c0 = make_uint4(pk(xm[0][i], xm[1][i]), pk(xm[2][i], xm[3][i]),
                                  pk(gx[0][i], gx[1][i]), pk(gx[2][i], gx[3][i]));
            uint4 c1 = make_uint4(pk(gy[0][i], gy[1][i]), pk(gy[2][i], gy[3][i]),
                                  pk(dn[0][i], dn[1][i]), pk(dn[2][i], dn[3][i]));
            *(uint4*)&rowp[8 * ((2 * wv)     ^ s)] = c0;   // knew 16wv..+7  : x | gx
            *(uint4*)&rowp[8 * ((2 * wv + 1) ^ s)] = c1;   // knew 16wv+8..15: gy | dna/pad
        }
    }

    const int fj  = lane & 15;   // A-row / B-col / D-col
    const int fg  = lane >> 4;   // k-group (A/B), row-group (D)
    const int sfj = fj & 7;      // h-buffer swizzle
    const int f4  = fj >> 2;     // feat read swizzle base: sg(g4) = (4*g4 + f4) & 7

    // ---- weight fragments: global bf16 -> registers (issued before barrier) ----
    const u16* w1b = wb;             // [128][64] (k-permuted)
    const u16* w2b = wb + 128 * 64;  // [16][128]
    bf8 a1[8][2];
    #pragma unroll
    for (int m = 0; m < 8; ++m) {
        #pragma unroll
        for (int kt = 0; kt < 2; ++kt)
            a1[m][kt] = *(const bf8*)&w1b[(16 * m + fj) * 64 + 32 * kt + 8 * fg];
    }
    bf8 a2[4];
    #pragma unroll
    for (int kt = 0; kt < 4; ++kt)
        a2[kt] = *(const bf8*)&w2b[fj * 128 + 32 * kt + 8 * fg];

    __syncthreads();   // feature phase is cross-wave

    // ---- B-frags: g4=0 just-in-time, g4=1 pre-read (rows overlaid by g4=0's h).
    //      Program order + in-order per-wave DS guarantees these return pre-overlay data.
    bf8 b00, b01, p10, p11;
    {
        const int r0 = wv * 64 +  0 + fj;   const int s0 = f4;            // (0*4+f4)&7
        const int r1 = wv * 64 + 16 + fj;   const int s1 = (4 + f4) & 7;  // (1*4+f4)&7
        b00 = *(const bf8*)&feat_lds[r0 * 64 + 8 * ((0 + fg) ^ s0)];
        b01 = *(const bf8*)&feat_lds[r0 * 64 + 8 * ((4 + fg) ^ s0)];
        p10 = *(const bf8*)&feat_lds[r1 * 64 + 8 * ((0 + fg) ^ s1)];
        p11 = *(const bf8*)&feat_lds[r1 * 64 + 8 * ((4 + fg) ^ s1)];
    }

    u16* hwv = &feat_lds[wv * 4096];   // h [16 px][128 k] over rows wv*64 .. +31

    #pragma unroll
    for (int g4 = 0; g4 < 4; ++g4) {
        bf8 b0, b1;
        if (g4 == 0)      { b0 = b00; b1 = b01; }
        else if (g4 == 1) { b0 = p10; b1 = p11; }
        else {
            const int r  = wv * 64 + g4 * 16 + fj;     // rows +32..63: never overlaid
            const int sg = (4 * g4 + f4) & 7;
            b0 = *(const bf8*)&feat_lds[r * 64 + 8 * ((0 + fg) ^ sg)];
            b1 = *(const bf8*)&feat_lds[r * 64 + 8 * ((4 + fg) ^ sg)];
        }

        // ---- layer 1 in two m-halves (16-reg accumulator) ----
        #pragma unroll
        for (int mh = 0; mh < 2; ++mh) {
            f32x4 hc[4];
            #pragma unroll
            for (int mm = 0; mm < 4; ++mm) {
                const int m = mh * 4 + mm;
                f32x4 z = {0.f, 0.f, 0.f, 0.f};
                z = __builtin_amdgcn_mfma_f32_16x16x32_bf16(a1[m][0], b0, z, 0, 0, 0);
                hc[mm] = __builtin_amdgcn_mfma_f32_16x16x32_bf16(a1[m][1], b1, z, 0, 0, 0);
            }
            #pragma unroll
            for (int mm = 0; mm < 4; ++mm) {
                const int m = mh * 4 + mm;
                float h0 = fmaxf(hc[mm][0], 0.f), h1 = fmaxf(hc[mm][1], 0.f);
                float h2 = fmaxf(hc[mm][2], 0.f), h3 = fmaxf(hc[mm][3], 0.f);
                *(uint2*)&hwv[fj * 128 + 8 * ((2 * m + (fg >> 1)) ^ sfj) + 4 * (fg & 1)] =
                    make_uint2(pk(h0, h1), pk(h2, h3));
            }
        }

        // layer 2: h read-back (in-order DS; compiler inserts counted lgkmcnt)
        f32x4 uacc = {0.f, 0.f, 0.f, 0.f};
        #pragma unroll
        for (int kt = 0; kt < 4; ++kt) {
            bf8 b2 = *(const bf8*)&hwv[fj * 128 + 8 * ((4 * kt + fg) ^ sfj)];
            uacc = __builtin_amdgcn_mfma_f32_16x16x32_bf16(a2[kt], b2, uacc, 0, 0, 0);
        }

        const int xo = wv * 64 + g4 * 16 + fj;
        float* po = out + (((size_t)(b * STATE + 4 * fg)) * HH + y) * WW + xo;
        #pragma unroll
        for (int rr = 0; rr < 4; ++rr)
            po[(size_t)rr * HW] = uacc[rr];
    }
}

extern "C" void kernel_launch(void* const* d_in, const int* in_sizes, int n_in,
                              void* d_out, int out_size, void* d_ws, size_t ws_size,
                              hipStream_t stream) {
    const float* x   = (const float*)d_in[0];
    const float* dna = (const float*)d_in[1];
    const float* w1  = (const float*)d_in[2];
    const float* w2  = (const float*)d_in[3];
    float* out = (float*)d_out;
    u16* wb = (u16*)d_ws;   // 10240 u16 = 20 KB

    prep_weights<<<dim3(40), dim3(256), 0, stream>>>(w1, w2, wb);

    const int B = in_sizes[0] / (STATE * HH * WW);   // 16
    update_net10<<<dim3(B * HH), dim3(256), 0, stream>>>(x, dna, wb, out);
}